// Round 11
// baseline (321.054 us; speedup 1.0000x reference)
//
#include <hip/hip_runtime.h>

#define L 4096
#define HH 64
#define CC 128
#define BB 2

typedef _Float16 f16;
typedef _Float16 f16x8 __attribute__((ext_vector_type(8)));
typedef float f32x4 __attribute__((ext_vector_type(4)));

__device__ __forceinline__ void gl_lds16(const f16* g, f16* l) {
  __builtin_amdgcn_global_load_lds(
      (const __attribute__((address_space(1))) void*)g,
      (__attribute__((address_space(3))) void*)l, 16, 0, 0);
}

// sigma: involution converting row-major flat <-> col-major flat (64x64)
__device__ __forceinline__ int sigma_(int j) { return ((j & 63) << 6) | (j >> 6); }

// full 9-tap fused score from S (reference wrap semantics), scalar (edge columns)
__device__ float fuse9(const f16* __restrict__ Sb, int k, int j) {
  float acc = 0.f;
  int cK = sigma_(k), cQ = sigma_(j);
#pragma unroll
  for (int u = -1; u <= 1; ++u) {
    int a = cK + u, bq = cQ + u;
    if ((unsigned)a < L && (unsigned)bq < L) {
      int r = sigma_(a), c = sigma_(bq);
#pragma unroll
      for (int t = -1; t <= 1; ++t) {
        int rr = r + t, cc = c + t;
        if ((unsigned)rr < L && (unsigned)cc < L) acc += (float)Sb[(size_t)rr * L + cc];
      }
    }
  }
  return acc;
}

// ---------------- kernel 0a: repack [c][u] f32 -> [u][c] f16 (b and f), zero zeropage ----
__global__ __launch_bounds__(256) void k_repack(
    const float* __restrict__ b, const float* __restrict__ f,
    f16* __restrict__ bT, f16* __restrict__ fT, f16* __restrict__ zp) {
  __shared__ float tile[128][65];
  int u0 = blockIdx.x * 64;
  int z = blockIdx.y;            // batch*2 + tensor
  int batch = z >> 1;
  const float* src = ((z & 1) ? f : b) + (size_t)batch * CC * L;
  f16* dst = ((z & 1) ? fT : bT) + (size_t)batch * L * CC;
  int tid = threadIdx.x;
  if (blockIdx.x == 0 && z == 0 && tid < 32) zp[tid] = (f16)0.f;
#pragma unroll
  for (int i = 0; i < 32; ++i) {
    int idx = i * 256 + tid;
    int c = idx >> 6, ux = idx & 63;
    tile[c][ux] = src[(size_t)c * L + u0 + ux];
  }
  __syncthreads();
#pragma unroll
  for (int j = 0; j < 4; ++j) {
    int t2 = j * 256 + tid;
    int u = t2 >> 4, ch = t2 & 15;
    f16x8 v;
#pragma unroll
    for (int e = 0; e < 8; ++e) v[e] = (f16)tile[ch * 8 + e][u];
    *(f16x8*)(dst + (size_t)(u0 + u) * CC + ch * 8) = v;
  }
}

// ---------------- kernel 0b: ssq[batch][u] = sum_c b[c][u]^2 -----------------------------
__global__ __launch_bounds__(256) void k_ssq(const float* __restrict__ b, float* __restrict__ ssq) {
  int u = blockIdx.x * 256 + threadIdx.x;
  int batch = blockIdx.y;
  const float* bp = b + (size_t)batch * CC * L + u;
  float s = 0.f;
#pragma unroll 4
  for (int c = 0; c < CC; ++c) { float v = bp[(size_t)c * L]; s += v * v; }
  ssq[batch * L + u] = s;
}

// ---------------- kernel 0c: inv_n[batch][k] = 1/max(sqrt(sum_{r valid} ssq),1e-4) -------
__global__ void k_norm(const float* __restrict__ ssq, float* __restrict__ inv_n) {
  int gi = blockIdx.x * 256 + threadIdx.x;
  if (gi >= BB * L) return;
  int batch = gi >> 12, k = gi & (L - 1);
  int ky = k >> 6, kx = k & 63;
  float s = 0.f;
#pragma unroll
  for (int dy = -1; dy <= 1; ++dy)
#pragma unroll
    for (int dx = -1; dx <= 1; ++dx) {
      if ((unsigned)(ky + dy) < 64 && (unsigned)(kx + dx) < 64)
        s += ssq[batch * L + k + dy * 64 + dx];
    }
  inv_n[gi] = 1.f / fmaxf(sqrtf(s), 1e-4f);
}

// ---------------- kernel 1b: shifted+masked f16 copies of b (vectorized) -----------------
__global__ __launch_bounds__(256) void k_prep_bm(const float* __restrict__ b, f16* __restrict__ bm) {
  int idx = blockIdx.x * 256 + threadIdx.x;  // x8 elements
  int e8 = idx * 8;
  int k0 = e8 & (L - 1);
  int c = (e8 >> 12) & (CC - 1);
  int bt = e8 >> 19;            // tap*2 + batch
  int batch = bt & 1;
  int tap = bt >> 1;
  int di = 1 - (tap >> 1), dj = 1 - (tap & 1);
  int ky = k0 >> 6, kx0 = k0 & 63;
  const float* src = b + ((size_t)batch * CC + c) * L + k0 + di * 64 + dj;
  bool rowok = (ky + di) < 64;
  f16x8 v;
#pragma unroll
  for (int e = 0; e < 8; ++e) {
    float x = (rowok && (kx0 + e + dj) < 64) ? src[e] : 0.f;
    v[e] = (f16)x;
  }
  *(f16x8*)(bm + (size_t)e8) = v;
}

// ---------------- kernel 1c: mask validity mm[k] -----------------------------------------
__global__ void k_prep_mm(const float* __restrict__ mask, float* __restrict__ mmv) {
  int k = blockIdx.x * 256 + threadIdx.x;
  if (k >= L) return;
  int ky = k >> 6, kx = k & 63;
  float s = 0.f;
  for (int i = 0; i < 3; ++i)
    for (int j = 0; j < 3; ++j) {
      int yy = ky + i - 1, xx = kx + j - 1;
      if (yy >= 0 && yy < 64 && xx >= 0 && xx < 64) s += mask[yy * 64 + xx];
    }
  mmv[k] = (s == 0.f) ? 1.f : 0.f;
}

// ---------------- kernel 2: implicit-patch scores GEMM, 2-phase double-buffered ----------
__global__ __launch_bounds__(256) void k_gemm_scores(
    const f16* __restrict__ bT, const f16* __restrict__ fT,
    const float* __restrict__ inv_n, const f16* __restrict__ zp,
    f16* __restrict__ S) {
  __shared__ f16 As[2][128 * 64];
  __shared__ f16 Bs[2][128 * 64];
  int qt = blockIdx.x, kt = blockIdx.y, batch = blockIdx.z;
  int tid = threadIdx.x, wid = tid >> 6, lane = tid & 63;
  int wr = wid >> 1, wc = wid & 1;
  const f16* A0 = bT + (size_t)batch * L * CC;
  const f16* B0 = fT + (size_t)batch * L * CC;
  f32x4 acc[4][4] = {};
  int rA = wr * 64 + (lane & 15);
  int rB = wc * 64 + (lane & 15);

  const f16* baseA_[4]; const f16* baseB_[4];
  int offL_[4];
  unsigned mA_[4], mB_[4];
#pragma unroll
  for (int i = 0; i < 4; ++i) {
    int chunk = (i * 4 + wid) * 64 + lane;         // 0..1023
    int row = chunk >> 3;                          // 0..127
    int lg = (lane & 7) ^ (row & 7);               // pre-swizzled source chunk
    int k = kt * 128 + row;
    int q = qt * 128 + row;
    baseA_[i] = A0 + (size_t)k * CC + lg * 8;
    baseB_[i] = B0 + (size_t)q * CC + lg * 8;
    offL_[i] = chunk * 8;
    int ky = k >> 6, kx = k & 63, qy = q >> 6, qx = q & 63;
    unsigned ma = 0, mb = 0;
#pragma unroll
    for (int rr = 0; rr < 9; ++rr) {
      int dy = rr / 3 - 1, dx = rr - (rr / 3) * 3 - 1;
      if ((unsigned)(ky + dy) < 64u && (unsigned)(kx + dx) < 64u) ma |= 1u << rr;
      if ((unsigned)(qy + dy) < 64u && (unsigned)(qx + dx) < 64u) mb |= 1u << rr;
    }
    mA_[i] = ma; mB_[i] = mb;
  }

#define STAGE_T(tt, bsel)                                                     \
  do {                                                                        \
    int rr_ = (tt) >> 1, half_ = (tt) & 1;                                    \
    int dy_ = rr_ / 3 - 1, dx_ = rr_ - (rr_ / 3) * 3 - 1;                     \
    int doff_ = (dy_ * 64 + dx_) * CC + half_ * 64;                           \
    _Pragma("unroll")                                                         \
    for (int i = 0; i < 4; ++i) {                                             \
      gl_lds16(((mA_[i] >> rr_) & 1u) ? (baseA_[i] + doff_) : zp,             \
               &As[bsel][0] + offL_[i]);                                      \
      gl_lds16(((mB_[i] >> rr_) & 1u) ? (baseB_[i] + doff_) : zp,             \
               &Bs[bsel][0] + offL_[i]);                                      \
    }                                                                         \
  } while (0)

  STAGE_T(0, 0);
  int cur = 0;
#pragma unroll 1
  for (int t = 0; t < 18; ++t) {
    __syncthreads();
    if (t < 17) STAGE_T(t + 1, cur ^ 1);
    const f16* Ab = &As[cur][0];
    const f16* Bb = &Bs[cur][0];
#pragma unroll
    for (int h2 = 0; h2 < 2; ++h2) {
      int cb = h2 * 4 + (lane >> 4);
      f16x8 af[4], bf[4];
#pragma unroll
      for (int m = 0; m < 4; ++m) {
        int row = rA + m * 16;
        af[m] = *(const f16x8*)(Ab + row * 64 + ((cb ^ (row & 7)) * 8));
      }
#pragma unroll
      for (int n = 0; n < 4; ++n) {
        int row = rB + n * 16;
        bf[n] = *(const f16x8*)(Bb + row * 64 + ((cb ^ (row & 7)) * 8));
      }
#pragma unroll
      for (int m = 0; m < 4; ++m)
#pragma unroll
        for (int n = 0; n < 4; ++n)
          acc[m][n] = __builtin_amdgcn_mfma_f32_16x16x32_f16(af[m], bf[n], acc[m][n], 0, 0, 0);
    }
    cur ^= 1;
  }
#undef STAGE_T

  f16* Srow = S + (size_t)batch * L * L;
  int kbase = kt * 128 + wr * 64 + (lane >> 4) * 4;
  int qbase = qt * 128 + wc * 64 + (lane & 15);
#pragma unroll
  for (int m = 0; m < 4; ++m) {
    f32x4 invv = *(const f32x4*)(inv_n + (size_t)batch * L + kbase + m * 16);
#pragma unroll
    for (int r = 0; r < 4; ++r) {
      f16* dst = Srow + (size_t)(kbase + m * 16 + r) * L + qbase;
#pragma unroll
      for (int n = 0; n < 4; ++n) dst[n * 16] = (f16)(acc[m][n][r] * invv[r]);
    }
  }
}

// ---------------- kernel 3: fused stencil -> T3 + online softmax partials ----------------
__global__ __launch_bounds__(256) void k_fuse_stats(
    const f16* __restrict__ S, const float* __restrict__ mmv,
    float* __restrict__ T3, float* __restrict__ pm, float* __restrict__ pl) {
  int tid = threadIdx.x;
  if (tid >= 247) return;
  int jc = blockIdx.x, kc = blockIdx.y, batch = blockIdx.z;
  int g = jc * 247 + tid;                  // 0..493
  int q0 = 72 + g * 8;                     // aligned, fully interior group
  const f16* Sb = S + (size_t)batch * L * L;
  float* Tb = T3 + (size_t)batch * L * L;
  float m8[8], l8[8];
#pragma unroll
  for (int e = 0; e < 8; ++e) { m8[e] = -3.0e38f; l8[e] = 0.f; }
  int cnt = 0;
  int k0 = kc * 16;
  for (int kk = 0; kk < 16; ++kk) {
    int k = k0 + kk;
    if (mmv[k] == 0.f) { ++cnt; continue; }
    float acc[8] = {0.f, 0.f, 0.f, 0.f, 0.f, 0.f, 0.f, 0.f};
    int cK = sigma_(k);
#pragma unroll
    for (int u = -1; u <= 1; ++u) {
      int a = cK + u;
      if ((unsigned)a >= L) continue;
      int r = sigma_(a);                   // = k + 64u for interior k
      const f16* cb = Sb + (size_t)r * L + (q0 + 64 * u);
      {
        f16x8 v = *(const f16x8*)cb;
#pragma unroll
        for (int e = 0; e < 8; ++e) acc[e] += (float)v[e];
      }
      if (r >= 1) {
        const f16* rm = cb - L;
        f16x8 v = *(const f16x8*)rm;
        acc[0] += (float)rm[-1];
#pragma unroll
        for (int e = 1; e < 8; ++e) acc[e] += (float)v[e - 1];
      }
      if (r <= L - 2) {
        const f16* rp = cb + L;
        f16x8 v = *(const f16x8*)rp;
#pragma unroll
        for (int e = 0; e < 7; ++e) acc[e] += (float)v[e + 1];
        acc[7] += (float)rp[8];
      }
    }
#pragma unroll
    for (int e = 0; e < 8; ++e) acc[e] *= 10.f;
    float* trow = Tb + (size_t)k * L + q0;
    *(f32x4*)trow = *(f32x4*)&acc[0];
    *(f32x4*)(trow + 4) = *(f32x4*)&acc[4];
#pragma unroll
    for (int e = 0; e < 8; ++e) {
      float nm = fmaxf(m8[e], acc[e]);
      l8[e] = l8[e] * __expf(m8[e] - nm) + __expf(acc[e] - nm);
      m8[e] = nm;
    }
  }
  float fc = (float)cnt;
  float om[8], ol[8];
#pragma unroll
  for (int e = 0; e < 8; ++e) {
    float nm = fmaxf(m8[e], 0.f);
    ol[e] = l8[e] * __expf(m8[e] - nm) + fc * __expf(-nm);
    om[e] = nm;
  }
  float* pmp = pm + (size_t)kc * (BB * L) + (size_t)batch * L + q0;
  float* plp = pl + (size_t)kc * (BB * L) + (size_t)batch * L + q0;
  *(f32x4*)pmp = *(f32x4*)&om[0]; *(f32x4*)(pmp + 4) = *(f32x4*)&om[4];
  *(f32x4*)plp = *(f32x4*)&ol[0]; *(f32x4*)(plp + 4) = *(f32x4*)&ol[4];
}

// ---------------- kernel 3e: edge q columns (144 cols), scalar fuse9 ---------------------
__global__ __launch_bounds__(256) void k_fuse_stats_edge(
    const f16* __restrict__ S, const float* __restrict__ mmv,
    float* __restrict__ T3, float* __restrict__ pm, float* __restrict__ pl) {
  int tid = threadIdx.x;
  if (tid >= 144) return;
  int q = (tid < 72) ? tid : (4024 + tid - 72);
  int kc = blockIdx.x, batch = blockIdx.y;
  const f16* Sb = S + (size_t)batch * L * L;
  float* Tb = T3 + (size_t)batch * L * L;
  float m = -3.0e38f, l = 0.f;
  int cnt = 0;
  int k0 = kc * 16;
  for (int kk = 0; kk < 16; ++kk) {
    int k = k0 + kk;
    if (mmv[k] == 0.f) { ++cnt; continue; }
    float logit = 10.f * fuse9(Sb, k, q);
    Tb[(size_t)k * L + q] = logit;
    float nm = fmaxf(m, logit);
    l = l * __expf(m - nm) + __expf(logit - nm);
    m = nm;
  }
  float nm = fmaxf(m, 0.f);
  l = l * __expf(m - nm) + (float)cnt * __expf(-nm);
  pm[(size_t)kc * (BB * L) + (size_t)batch * L + q] = nm;
  pl[(size_t)kc * (BB * L) + (size_t)batch * L + q] = l;
}

// ---------------- kernel 3b: combine partials; store M and 1/L (parallelized) ------------
__global__ __launch_bounds__(256) void k_softmax_reduce(
    const float* __restrict__ pm, const float* __restrict__ pl,
    float* __restrict__ Mq, float* __restrict__ invLq) {
  __shared__ float sm[4][64], sl[4][64];
  int tid = threadIdx.x;
  int ql = tid & 63, part = tid >> 6;
  int qi = blockIdx.x * 64 + ql;
  float m = -3.0e38f, l = 0.f;
  int i0 = part * 64;
#pragma unroll 4
  for (int i = i0; i < i0 + 64; ++i) {
    float pmv = pm[(size_t)i * (BB * L) + qi];
    float plv = pl[(size_t)i * (BB * L) + qi];
    float nm = fmaxf(m, pmv);
    l = l * __expf(m - nm) + plv * __expf(pmv - nm);
    m = nm;
  }
  sm[part][ql] = m; sl[part][ql] = l;
  __syncthreads();
  if (part == 0) {
    float M = sm[0][ql];
#pragma unroll
    for (int p = 1; p < 4; ++p) M = fmaxf(M, sm[p][ql]);
    float Ls = 0.f;
#pragma unroll
    for (int p = 0; p < 4; ++p) Ls += sl[p][ql] * __expf(sm[p][ql] - M);
    Mq[qi] = M;
    invLq[qi] = 1.f / Ls;
  }
}

// ---------------- kernel 5: aggregation, transposed-task B-staging + async split ---------
// Task (pp, kg) fixed per thread across k-loop: loads T3 column-wise (8 rows x 1 col),
// exp in registers during MFMA phase, single ds_write_b128 per task per step.
__global__ __launch_bounds__(512) void k_agg(
    const float* __restrict__ T3, const float* __restrict__ mmv,
    const float* __restrict__ Mq, const float* __restrict__ invLq,
    const f16* __restrict__ bm, float* __restrict__ part) {
  __shared__ f16 Asm[512 * 32];   // [R=tap*128+c][32kk], chunk-swizzled: phys = log ^ ((R>>1)&3)
  __shared__ f16 Bt[136 * 40];    // [pp][kk], kk-chunk swizzled: phys = kg ^ ((pp>>3)&3)
  int pt = blockIdx.x, ks = blockIdx.y, batch = blockIdx.z;
  int p0 = pt * 64;
  int tid = threadIdx.x, wid = tid >> 6, lane = tid & 63;
  int wr = wid >> 1, wc = wid & 1;
  const float* Tb = T3 + (size_t)batch * L * L;

  // ---- hoisted A staging state ----
  const f16* gA_[4]; f16* lA_[4];
#pragma unroll
  for (int i = 0; i < 4; ++i) {
    int R = wid * 64 + i * 16 + (lane >> 2);
    int tap = R >> 7, c = R & 127;
    int chl = (lane & 3) ^ ((R >> 1) & 3);
    gA_[i] = bm + (((size_t)(tap * 2 + batch) * CC + c) * L) + chl * 8;
    lA_[i] = Asm + R * 32 + (lane & 3) * 8;
  }

  // ---- hoisted B-task state (tasks: pp in [0,136), kg in [0,4); 544 total) ----
  bool act1 = (tid < 32);
  int pp_[2], kg_[2]; bool qok_[2]; float M_[2], iL_[2];
  const float* tb_[2]; f16* bw_[2];
#pragma unroll
  for (int s = 0; s < 2; ++s) {
    int tau = tid + s * 512;
    int ppv = tau % 136, kgv = tau / 136;
    if (tau >= 544) { ppv = 0; kgv = 0; }
    pp_[s] = ppv; kg_[s] = kgv;
    int q = p0 + ppv;
    bool qok = q < L;
    int qc = qok ? q : (L - 1);
    qok_[s] = qok;
    M_[s] = Mq[(size_t)batch * L + qc];
    iL_[s] = invLq[(size_t)batch * L + qc];
    tb_[s] = Tb + (size_t)(kgv * 8) * L + qc;
    bw_[s] = Bt + ppv * 40 + ((kgv ^ ((ppv >> 3) & 3)) * 8);
  }

  f16x8 vv_[2];
  int kend = ks * 1024 + 1024;

#define LOADB(K0)                                                             \
  do {                                                                        \
    _Pragma("unroll")                                                         \
    for (int s = 0; s < 2; ++s) {                                             \
      if (s == 1 && !act1) break;                                             \
      const float* tp = tb_[s] + (size_t)(K0) * L;                            \
      f32x4 ma = *(const f32x4*)(mmv + (K0) + kg_[s] * 8);                    \
      f32x4 mb = *(const f32x4*)(mmv + (K0) + kg_[s] * 8 + 4);                \
      float t[8];                                                             \
      _Pragma("unroll")                                                       \
      for (int j = 0; j < 8; ++j) t[j] = tp[(size_t)j * L];                   \
      f16 v[8];                                                               \
      _Pragma("unroll")                                                       \
      for (int j = 0; j < 8; ++j) {                                           \
        float mmj = (j < 4) ? ma[j] : mb[j - 4];                              \
        v[j] = (qok_[s] && mmj != 0.f)                                        \
                   ? (f16)(__expf(t[j] - M_[s]) * iL_[s]) : (f16)0.f;         \
      }                                                                       \
      vv_[s] = *(f16x8*)v;                                                    \
    }                                                                         \
  } while (0)

  LOADB(ks * 1024);               // prologue
  f32x4 acc[2][2] = {};
#pragma unroll 1
  for (int k0 = ks * 1024; k0 < kend; k0 += 32) {
    __syncthreads();              // prior MFMA done reading Asm/Bt
    // B write phase (regs -> LDS), 1-2 vector stores
    *(f16x8*)bw_[0] = vv_[0];
    if (act1) *(f16x8*)bw_[1] = vv_[1];
    // A staging (async global->LDS)
#pragma unroll
    for (int i = 0; i < 4; ++i) gl_lds16(gA_[i] + k0, lA_[i]);
    __syncthreads();              // drains ds_writes + gl_lds
    // MFMA phase
#pragma unroll
    for (int tap = 0; tap < 4; ++tap) {
      int dlt = (tap >> 1) * 64 + (tap & 1);
      f16x8 af[2], bf[2];
#pragma unroll
      for (int m = 0; m < 2; ++m) {
        int R = tap * 128 + wr * 32 + m * 16 + (lane & 15);
        int ph = (lane >> 4) ^ ((R >> 1) & 3);
        af[m] = *(const f16x8*)(Asm + R * 32 + ph * 8);
      }
#pragma unroll
      for (int n = 0; n < 2; ++n) {
        int pp = wc * 32 + n * 16 + (lane & 15) + dlt;
        int ph = (lane >> 4) ^ ((pp >> 3) & 3);
        bf[n] = *(const f16x8*)(Bt + pp * 40 + ph * 8);
      }
#pragma unroll
      for (int m = 0; m < 2; ++m)
#pragma unroll
        for (int n = 0; n < 2; ++n)
          acc[m][n] = __builtin_amdgcn_mfma_f32_16x16x32_f16(af[m], bf[n], acc[m][n], 0, 0, 0);
    }
    // issue next-step T3/mmv loads + exp (overlaps MFMA pipe execution)
    if (k0 + 32 < kend) LOADB(k0 + 32);
  }
#undef LOADB

  int cb = wr * 32 + (lane >> 4) * 4;
  int pb = p0 + wc * 32 + (lane & 15);
#pragma unroll
  for (int m = 0; m < 2; ++m)
#pragma unroll
    for (int n = 0; n < 2; ++n)
#pragma unroll
      for (int r = 0; r < 4; ++r) {
        int c = cb + m * 16 + r;
        int p = pb + n * 16;
        part[(((size_t)ks * 2 + batch) * CC + c) * L + p] = acc[m][n][r];
      }
}

// ---------------- kernel 5b: sum K-split partials, scale, border mask (vectorized) -------
__global__ __launch_bounds__(256) void k_agg_reduce(const float* __restrict__ part, float* __restrict__ out) {
  int idx = (blockIdx.x * 256 + threadIdx.x) * 4;   // 2*128*4096 total
  f32x4 s = {0.f, 0.f, 0.f, 0.f};
#pragma unroll
  for (int ks = 0; ks < 4; ++ks) {
    f32x4 v = *(const f32x4*)(part + (size_t)ks * (2 * CC * L) + idx);
#pragma unroll
    for (int e = 0; e < 4; ++e) s[e] += v[e];
  }
  int p = idx & (L - 1);
  int u = p >> 6, vv = p & 63;
  f32x4 o;
#pragma unroll
  for (int e = 0; e < 4; ++e) o[e] = (u < 63 && (vv + e) < 63) ? s[e] * 0.25f : 0.f;
  *(f32x4*)(out + idx) = o;
}

extern "C" void kernel_launch(void* const* d_in, const int* in_sizes, int n_in,
                              void* d_out, int out_size, void* d_ws, size_t ws_size,
                              hipStream_t stream) {
  const float* f = (const float*)d_in[0];
  const float* b = (const float*)d_in[1];
  const float* mask = (const float*)d_in[2];
  float* out = (float*)d_out;
  char* ws = (char*)d_ws;

  float* T3  = (float*)(ws + 0);           // 134,217,728
  f16* S     = (f16*)(ws + 134217728);     // 67,108,864
  f16* bm    = (f16*)(ws + 201326592);     // 8,388,608
  float* part= (float*)(ws + 209715200);   // 16,777,216
  float* pm  = (float*)(ws + 226492416);   // 8,388,608
  float* pl  = (float*)(ws + 234881024);   // 8,388,608
  float* mmv = (float*)(ws + 243269632);   // 16,384
  float* Mq  = (float*)(ws + 243286016);   // 32,768
  float* iLq = (float*)(ws + 243318784);   // 32,768
  f16* bT    = (f16*)(ws + 243351552);     // 2,097,152
  f16* fT    = (f16*)(ws + 245448704);     // 2,097,152
  float* ssq = (float*)(ws + 247545856);   // 32,768
  float* invn= (float*)(ws + 247578624);   // 32,768
  f16* zp    = (f16*)(ws + 247611392);     // 64

  k_repack<<<dim3(64, 4), dim3(256), 0, stream>>>(b, f, bT, fT, zp);
  k_ssq<<<dim3(16, 2), dim3(256), 0, stream>>>(b, ssq);
  k_norm<<<dim3(32), dim3(256), 0, stream>>>(ssq, invn);
  k_prep_bm<<<dim3(2048), dim3(256), 0, stream>>>(b, bm);
  k_prep_mm<<<dim3(16), dim3(256), 0, stream>>>(mask, mmv);
  k_gemm_scores<<<dim3(32, 32, 2), dim3(256), 0, stream>>>(bT, fT, invn, zp, S);
  k_fuse_stats<<<dim3(2, 256, 2), dim3(256), 0, stream>>>(S, mmv, T3, pm, pl);
  k_fuse_stats_edge<<<dim3(256, 2), dim3(256), 0, stream>>>(S, mmv, T3, pm, pl);
  k_softmax_reduce<<<dim3(128), dim3(256), 0, stream>>>(pm, pl, Mq, iLq);
  k_agg<<<dim3(64, 4, 2), dim3(512), 0, stream>>>(T3, mmv, Mq, iLq, bm, part);
  k_agg_reduce<<<dim3(1024), dim3(256), 0, stream>>>(part, out);
}

// Round 12
// 310.437 us; speedup vs baseline: 1.0342x; 1.0342x over previous
//
#include <hip/hip_runtime.h>

#define L 4096
#define HH 64
#define CC 128
#define BB 2

typedef _Float16 f16;
typedef _Float16 f16x8 __attribute__((ext_vector_type(8)));
typedef float f32x4 __attribute__((ext_vector_type(4)));

__device__ __forceinline__ void gl_lds16(const f16* g, f16* l) {
  __builtin_amdgcn_global_load_lds(
      (const __attribute__((address_space(1))) void*)g,
      (__attribute__((address_space(3))) void*)l, 16, 0, 0);
}

// sigma: involution converting row-major flat <-> col-major flat (64x64)
__device__ __forceinline__ int sigma_(int j) { return ((j & 63) << 6) | (j >> 6); }

// full 9-tap fused score from S (reference wrap semantics), scalar (edge columns)
__device__ float fuse9(const f16* __restrict__ Sb, int k, int j) {
  float acc = 0.f;
  int cK = sigma_(k), cQ = sigma_(j);
#pragma unroll
  for (int u = -1; u <= 1; ++u) {
    int a = cK + u, bq = cQ + u;
    if ((unsigned)a < L && (unsigned)bq < L) {
      int r = sigma_(a), c = sigma_(bq);
#pragma unroll
      for (int t = -1; t <= 1; ++t) {
        int rr = r + t, cc = c + t;
        if ((unsigned)rr < L && (unsigned)cc < L) acc += (float)Sb[(size_t)rr * L + cc];
      }
    }
  }
  return acc;
}

// ---------------- kernel 0a: repack [c][u] f32 -> [u][c] f16 (b and f), zero zeropage ----
__global__ __launch_bounds__(256) void k_repack(
    const float* __restrict__ b, const float* __restrict__ f,
    f16* __restrict__ bT, f16* __restrict__ fT, f16* __restrict__ zp) {
  __shared__ float tile[128][65];
  int u0 = blockIdx.x * 64;
  int z = blockIdx.y;            // batch*2 + tensor
  int batch = z >> 1;
  const float* src = ((z & 1) ? f : b) + (size_t)batch * CC * L;
  f16* dst = ((z & 1) ? fT : bT) + (size_t)batch * L * CC;
  int tid = threadIdx.x;
  if (blockIdx.x == 0 && z == 0 && tid < 32) zp[tid] = (f16)0.f;
#pragma unroll
  for (int i = 0; i < 32; ++i) {
    int idx = i * 256 + tid;
    int c = idx >> 6, ux = idx & 63;
    tile[c][ux] = src[(size_t)c * L + u0 + ux];
  }
  __syncthreads();
#pragma unroll
  for (int j = 0; j < 4; ++j) {
    int t2 = j * 256 + tid;
    int u = t2 >> 4, ch = t2 & 15;
    f16x8 v;
#pragma unroll
    for (int e = 0; e < 8; ++e) v[e] = (f16)tile[ch * 8 + e][u];
    *(f16x8*)(dst + (size_t)(u0 + u) * CC + ch * 8) = v;
  }
}

// ---------------- kernel 0b: ssq[batch][u] = sum_c b[c][u]^2 -----------------------------
__global__ __launch_bounds__(256) void k_ssq(const float* __restrict__ b, float* __restrict__ ssq) {
  int u = blockIdx.x * 256 + threadIdx.x;
  int batch = blockIdx.y;
  const float* bp = b + (size_t)batch * CC * L + u;
  float s = 0.f;
#pragma unroll 4
  for (int c = 0; c < CC; ++c) { float v = bp[(size_t)c * L]; s += v * v; }
  ssq[batch * L + u] = s;
}

// ---------------- kernel 0c: inv_n[batch][k] = 1/max(sqrt(sum_{r valid} ssq),1e-4) -------
__global__ void k_norm(const float* __restrict__ ssq, float* __restrict__ inv_n) {
  int gi = blockIdx.x * 256 + threadIdx.x;
  if (gi >= BB * L) return;
  int batch = gi >> 12, k = gi & (L - 1);
  int ky = k >> 6, kx = k & 63;
  float s = 0.f;
#pragma unroll
  for (int dy = -1; dy <= 1; ++dy)
#pragma unroll
    for (int dx = -1; dx <= 1; ++dx) {
      if ((unsigned)(ky + dy) < 64 && (unsigned)(kx + dx) < 64)
        s += ssq[batch * L + k + dy * 64 + dx];
    }
  inv_n[gi] = 1.f / fmaxf(sqrtf(s), 1e-4f);
}

// ---------------- kernel 1b: shifted+masked f16 copies of b (vectorized) -----------------
__global__ __launch_bounds__(256) void k_prep_bm(const float* __restrict__ b, f16* __restrict__ bm) {
  int idx = blockIdx.x * 256 + threadIdx.x;  // x8 elements
  int e8 = idx * 8;
  int k0 = e8 & (L - 1);
  int c = (e8 >> 12) & (CC - 1);
  int bt = e8 >> 19;            // tap*2 + batch
  int batch = bt & 1;
  int tap = bt >> 1;
  int di = 1 - (tap >> 1), dj = 1 - (tap & 1);
  int ky = k0 >> 6, kx0 = k0 & 63;
  const float* src = b + ((size_t)batch * CC + c) * L + k0 + di * 64 + dj;
  bool rowok = (ky + di) < 64;
  f16x8 v;
#pragma unroll
  for (int e = 0; e < 8; ++e) {
    float x = (rowok && (kx0 + e + dj) < 64) ? src[e] : 0.f;
    v[e] = (f16)x;
  }
  *(f16x8*)(bm + (size_t)e8) = v;
}

// ---------------- kernel 1c: mask validity mm[k] -----------------------------------------
__global__ void k_prep_mm(const float* __restrict__ mask, float* __restrict__ mmv) {
  int k = blockIdx.x * 256 + threadIdx.x;
  if (k >= L) return;
  int ky = k >> 6, kx = k & 63;
  float s = 0.f;
  for (int i = 0; i < 3; ++i)
    for (int j = 0; j < 3; ++j) {
      int yy = ky + i - 1, xx = kx + j - 1;
      if (yy >= 0 && yy < 64 && xx >= 0 && xx < 64) s += mask[yy * 64 + xx];
    }
  mmv[k] = (s == 0.f) ? 1.f : 0.f;
}

// ---------------- kernel 1d: zcnt[chunk] = # masked rows in 8-row chunk ------------------
__global__ void k_zcnt(const float* __restrict__ mmv, float* __restrict__ zcnt) {
  int i = blockIdx.x * 256 + threadIdx.x;
  if (i >= 512) return;
  float s = 0.f;
#pragma unroll
  for (int r = 0; r < 8; ++r) s += (mmv[i * 8 + r] == 0.f) ? 1.f : 0.f;
  zcnt[i] = s;
}

// ---------------- kernel 2: implicit-patch scores GEMM, 2-phase double-buffered ----------
__global__ __launch_bounds__(256) void k_gemm_scores(
    const f16* __restrict__ bT, const f16* __restrict__ fT,
    const float* __restrict__ inv_n, const f16* __restrict__ zp,
    f16* __restrict__ S) {
  __shared__ f16 As[2][128 * 64];
  __shared__ f16 Bs[2][128 * 64];
  int qt = blockIdx.x, kt = blockIdx.y, batch = blockIdx.z;
  int tid = threadIdx.x, wid = tid >> 6, lane = tid & 63;
  int wr = wid >> 1, wc = wid & 1;
  const f16* A0 = bT + (size_t)batch * L * CC;
  const f16* B0 = fT + (size_t)batch * L * CC;
  f32x4 acc[4][4] = {};
  int rA = wr * 64 + (lane & 15);
  int rB = wc * 64 + (lane & 15);

  const f16* baseA_[4]; const f16* baseB_[4];
  int offL_[4];
  unsigned mA_[4], mB_[4];
#pragma unroll
  for (int i = 0; i < 4; ++i) {
    int chunk = (i * 4 + wid) * 64 + lane;         // 0..1023
    int row = chunk >> 3;                          // 0..127
    int lg = (lane & 7) ^ (row & 7);               // pre-swizzled source chunk
    int k = kt * 128 + row;
    int q = qt * 128 + row;
    baseA_[i] = A0 + (size_t)k * CC + lg * 8;
    baseB_[i] = B0 + (size_t)q * CC + lg * 8;
    offL_[i] = chunk * 8;
    int ky = k >> 6, kx = k & 63, qy = q >> 6, qx = q & 63;
    unsigned ma = 0, mb = 0;
#pragma unroll
    for (int rr = 0; rr < 9; ++rr) {
      int dy = rr / 3 - 1, dx = rr - (rr / 3) * 3 - 1;
      if ((unsigned)(ky + dy) < 64u && (unsigned)(kx + dx) < 64u) ma |= 1u << rr;
      if ((unsigned)(qy + dy) < 64u && (unsigned)(qx + dx) < 64u) mb |= 1u << rr;
    }
    mA_[i] = ma; mB_[i] = mb;
  }

#define STAGE_T(tt, bsel)                                                     \
  do {                                                                        \
    int rr_ = (tt) >> 1, half_ = (tt) & 1;                                    \
    int dy_ = rr_ / 3 - 1, dx_ = rr_ - (rr_ / 3) * 3 - 1;                     \
    int doff_ = (dy_ * 64 + dx_) * CC + half_ * 64;                           \
    _Pragma("unroll")                                                         \
    for (int i = 0; i < 4; ++i) {                                             \
      gl_lds16(((mA_[i] >> rr_) & 1u) ? (baseA_[i] + doff_) : zp,             \
               &As[bsel][0] + offL_[i]);                                      \
      gl_lds16(((mB_[i] >> rr_) & 1u) ? (baseB_[i] + doff_) : zp,             \
               &Bs[bsel][0] + offL_[i]);                                      \
    }                                                                         \
  } while (0)

  STAGE_T(0, 0);
  int cur = 0;
#pragma unroll 1
  for (int t = 0; t < 18; ++t) {
    __syncthreads();
    if (t < 17) STAGE_T(t + 1, cur ^ 1);
    const f16* Ab = &As[cur][0];
    const f16* Bb = &Bs[cur][0];
#pragma unroll
    for (int h2 = 0; h2 < 2; ++h2) {
      int cb = h2 * 4 + (lane >> 4);
      f16x8 af[4], bf[4];
#pragma unroll
      for (int m = 0; m < 4; ++m) {
        int row = rA + m * 16;
        af[m] = *(const f16x8*)(Ab + row * 64 + ((cb ^ (row & 7)) * 8));
      }
#pragma unroll
      for (int n = 0; n < 4; ++n) {
        int row = rB + n * 16;
        bf[n] = *(const f16x8*)(Bb + row * 64 + ((cb ^ (row & 7)) * 8));
      }
#pragma unroll
      for (int m = 0; m < 4; ++m)
#pragma unroll
        for (int n = 0; n < 4; ++n)
          acc[m][n] = __builtin_amdgcn_mfma_f32_16x16x32_f16(af[m], bf[n], acc[m][n], 0, 0, 0);
    }
    cur ^= 1;
  }
#undef STAGE_T

  f16* Srow = S + (size_t)batch * L * L;
  int kbase = kt * 128 + wr * 64 + (lane >> 4) * 4;
  int qbase = qt * 128 + wc * 64 + (lane & 15);
#pragma unroll
  for (int m = 0; m < 4; ++m) {
    f32x4 invv = *(const f32x4*)(inv_n + (size_t)batch * L + kbase + m * 16);
#pragma unroll
    for (int r = 0; r < 4; ++r) {
      f16* dst = Srow + (size_t)(kbase + m * 16 + r) * L + qbase;
#pragma unroll
      for (int n = 0; n < 4; ++n) dst[n * 16] = (f16)(acc[m][n][r] * invv[r]);
    }
  }
}

// ---------------- kernel 3: stencil -> P=exp(logit-m8) f16 + raw chunk stats -------------
// 8-row chunks; two-pass in registers. pmP/pl are RAW (no masked-count fold).
__global__ __launch_bounds__(256) void k_fuse_stats(
    const f16* __restrict__ S, const float* __restrict__ mmv,
    f16* __restrict__ P, float* __restrict__ pmP, float* __restrict__ pl) {
  int tid = threadIdx.x;
  if (tid >= 247) return;
  int jc = blockIdx.x, kc = blockIdx.y, batch = blockIdx.z;
  int g = jc * 247 + tid;                  // 0..493
  int q0 = 72 + g * 8;                     // aligned, fully interior group
  const f16* Sb = S + (size_t)batch * L * L;
  f16* Pb = P + (size_t)batch * L * L;
  float lg[8][8];
  float m8[8];
#pragma unroll
  for (int e = 0; e < 8; ++e) m8[e] = -3.0e38f;
  unsigned vmask = 0;
  int k0 = kc * 8;
  // pass 1: stencil -> logits in registers, per-column max
#pragma unroll
  for (int kk = 0; kk < 8; ++kk) {
    int k = k0 + kk;
    if (mmv[k] == 0.f) continue;
    vmask |= 1u << kk;
    float acc[8] = {0.f, 0.f, 0.f, 0.f, 0.f, 0.f, 0.f, 0.f};
    int cK = sigma_(k);
#pragma unroll
    for (int u = -1; u <= 1; ++u) {
      int a = cK + u;
      if ((unsigned)a >= L) continue;
      int r = sigma_(a);                   // = k + 64u for interior k
      const f16* cb = Sb + (size_t)r * L + (q0 + 64 * u);
      {
        f16x8 v = *(const f16x8*)cb;
#pragma unroll
        for (int e = 0; e < 8; ++e) acc[e] += (float)v[e];
      }
      if (r >= 1) {
        const f16* rm = cb - L;
        f16x8 v = *(const f16x8*)rm;
        acc[0] += (float)rm[-1];
#pragma unroll
        for (int e = 1; e < 8; ++e) acc[e] += (float)v[e - 1];
      }
      if (r <= L - 2) {
        const f16* rp = cb + L;
        f16x8 v = *(const f16x8*)rp;
#pragma unroll
        for (int e = 0; e < 7; ++e) acc[e] += (float)v[e + 1];
        acc[7] += (float)rp[8];
      }
    }
#pragma unroll
    for (int e = 0; e < 8; ++e) {
      float x = acc[e] * 10.f;
      lg[kk][e] = x;
      m8[e] = fmaxf(m8[e], x);
    }
  }
  // pass 2: write P = exp(lg - m8), accumulate l8
  float l8[8] = {0.f, 0.f, 0.f, 0.f, 0.f, 0.f, 0.f, 0.f};
#pragma unroll
  for (int kk = 0; kk < 8; ++kk) {
    if (!((vmask >> kk) & 1u)) continue;
    f16 v[8];
#pragma unroll
    for (int e = 0; e < 8; ++e) {
      float p = __expf(lg[kk][e] - m8[e]);
      l8[e] += p;
      v[e] = (f16)p;
    }
    *(f16x8*)(Pb + (size_t)(k0 + kk) * L + q0) = *(f16x8*)v;
  }
  float* pmp = pmP + (size_t)kc * (BB * L) + (size_t)batch * L + q0;
  float* plp = pl + (size_t)kc * (BB * L) + (size_t)batch * L + q0;
  *(f32x4*)pmp = *(f32x4*)&m8[0]; *(f32x4*)(pmp + 4) = *(f32x4*)&m8[4];
  *(f32x4*)plp = *(f32x4*)&l8[0]; *(f32x4*)(plp + 4) = *(f32x4*)&l8[4];
}

// ---------------- kernel 3e: edge q columns (144 cols), scalar fuse9 ---------------------
__global__ __launch_bounds__(256) void k_fuse_stats_edge(
    const f16* __restrict__ S, const float* __restrict__ mmv,
    f16* __restrict__ P, float* __restrict__ pmP, float* __restrict__ pl) {
  int tid = threadIdx.x;
  if (tid >= 144) return;
  int q = (tid < 72) ? tid : (4024 + tid - 72);
  int kc = blockIdx.x, batch = blockIdx.y;
  const f16* Sb = S + (size_t)batch * L * L;
  f16* Pb = P + (size_t)batch * L * L;
  float lgs[8];
  float m = -3.0e38f;
  unsigned vmask = 0;
  int k0 = kc * 8;
#pragma unroll
  for (int kk = 0; kk < 8; ++kk) {
    int k = k0 + kk;
    if (mmv[k] == 0.f) continue;
    vmask |= 1u << kk;
    float x = 10.f * fuse9(Sb, k, q);
    lgs[kk] = x;
    m = fmaxf(m, x);
  }
  float l = 0.f;
#pragma unroll
  for (int kk = 0; kk < 8; ++kk) {
    if (!((vmask >> kk) & 1u)) continue;
    float p = __expf(lgs[kk] - m);
    l += p;
    Pb[(size_t)(k0 + kk) * L + q] = (f16)p;
  }
  pmP[(size_t)kc * (BB * L) + (size_t)batch * L + q] = m;
  pl[(size_t)kc * (BB * L) + (size_t)batch * L + q] = l;
}

// ---------------- kernel 3b: combine raw partials + masked-count fold --------------------
__global__ __launch_bounds__(256) void k_softmax_reduce(
    const float* __restrict__ pmP, const float* __restrict__ pl,
    const float* __restrict__ zcnt,
    float* __restrict__ Mq, float* __restrict__ invLq) {
  __shared__ float sm[4][64], sl[4][64];
  int tid = threadIdx.x;
  int ql = tid & 63, part = tid >> 6;
  int qi = blockIdx.x * 64 + ql;
  float m = -3.0e38f, l = 0.f;
  int i0 = part * 128;
  float cntp = 0.f;
#pragma unroll 4
  for (int i = i0; i < i0 + 128; ++i) {
    float pmv = pmP[(size_t)i * (BB * L) + qi];
    float plv = pl[(size_t)i * (BB * L) + qi];
    float nm = fmaxf(m, pmv);
    l = l * __expf(m - nm) + plv * __expf(pmv - nm);
    m = nm;
    cntp += zcnt[i & 511];    // chunk id within batch (pm layout is chunk-major, qi covers batch)
  }
  if (cntp > 0.f) {
    float nm = fmaxf(m, 0.f);
    l = l * __expf(m - nm) + cntp * __expf(-nm);
    m = nm;
  }
  sm[part][ql] = m; sl[part][ql] = l;
  __syncthreads();
  if (part == 0) {
    float M = sm[0][ql];
#pragma unroll
    for (int p = 1; p < 4; ++p) M = fmaxf(M, sm[p][ql]);
    float Ls = 0.f;
#pragma unroll
    for (int p = 0; p < 4; ++p) Ls += sl[p][ql] * __expf(sm[p][ql] - M);
    Mq[qi] = M;
    invLq[qi] = 1.f / Ls;
  }
}

// ---------------- kernel 5: aggregation; Bt = P(f16) * exp(pmP - M) * iL -----------------
__global__ __launch_bounds__(512) void k_agg(
    const f16* __restrict__ P, const float* __restrict__ pmP,
    const float* __restrict__ mmv,
    const float* __restrict__ Mq, const float* __restrict__ invLq,
    const f16* __restrict__ bm, float* __restrict__ part) {
  __shared__ f16 Asm[512 * 32];   // [R=tap*128+c][32kk], chunk-swizzled
  __shared__ f16 Bt[136 * 40];    // [pp][kk], kk-chunk swizzled: phys = kg ^ ((pp>>3)&3)
  int pt = blockIdx.x, ks = blockIdx.y, batch = blockIdx.z;
  int p0 = pt * 64;
  int tid = threadIdx.x, wid = tid >> 6, lane = tid & 63;
  int wr = wid >> 1, wc = wid & 1;
  const f16* Pb = P + (size_t)batch * L * L;

  // ---- hoisted A staging state ----
  const f16* gA_[4]; f16* lA_[4];
#pragma unroll
  for (int i = 0; i < 4; ++i) {
    int R = wid * 64 + i * 16 + (lane >> 2);
    int tap = R >> 7, c = R & 127;
    int chl = (lane & 3) ^ ((R >> 1) & 3);
    gA_[i] = bm + (((size_t)(tap * 2 + batch) * CC + c) * L) + chl * 8;
    lA_[i] = Asm + R * 32 + (lane & 3) * 8;
  }

  // ---- hoisted B-task state (tasks: pp in [0,136), kg in [0,4); 544 total) ----
  bool act1 = (tid < 32);
  int kg_[2]; bool qok_[2]; float M_[2], iL_[2];
  const f16* tb_[2]; f16* bw_[2];
  size_t bq_[2];
#pragma unroll
  for (int s = 0; s < 2; ++s) {
    int tau = tid + s * 512;
    int ppv = tau % 136, kgv = tau / 136;
    if (tau >= 544) { ppv = 0; kgv = 0; }
    kg_[s] = kgv;
    int q = p0 + ppv;
    bool qok = q < L;
    int qc = qok ? q : (L - 1);
    qok_[s] = qok;
    M_[s] = Mq[(size_t)batch * L + qc];
    iL_[s] = invLq[(size_t)batch * L + qc];
    tb_[s] = Pb + (size_t)(kgv * 8) * L + qc;
    bq_[s] = (size_t)batch * L + qc;
    bw_[s] = Bt + ppv * 40 + ((kgv ^ ((ppv >> 3) & 3)) * 8);
  }

  f16x8 vv_[2];
  int kend = ks * 1024 + 1024;

#define LOADB(K0)                                                             \
  do {                                                                        \
    _Pragma("unroll")                                                         \
    for (int s = 0; s < 2; ++s) {                                             \
      if (s == 1 && !act1) break;                                             \
      const f16* tp = tb_[s] + (size_t)(K0) * L;                              \
      int ck = ((K0) >> 3) + kg_[s];                                          \
      float pmv = pmP[(size_t)ck * (BB * L) + bq_[s]];                        \
      float corr = qok_[s] ? __expf(pmv - M_[s]) * iL_[s] : 0.f;              \
      f32x4 ma = *(const f32x4*)(mmv + (K0) + kg_[s] * 8);                    \
      f32x4 mb = *(const f32x4*)(mmv + (K0) + kg_[s] * 8 + 4);                \
      f16 pv[8];                                                              \
      _Pragma("unroll")                                                       \
      for (int j = 0; j < 8; ++j) pv[j] = tp[(size_t)j * L];                  \
      f16 v[8];                                                               \
      _Pragma("unroll")                                                       \
      for (int j = 0; j < 8; ++j) {                                           \
        float mmj = (j < 4) ? ma[j] : mb[j - 4];                              \
        v[j] = (mmj != 0.f) ? (f16)((float)pv[j] * corr) : (f16)0.f;          \
      }                                                                       \
      vv_[s] = *(f16x8*)v;                                                    \
    }                                                                         \
  } while (0)

  LOADB(ks * 1024);               // prologue
  f32x4 acc[2][2] = {};
#pragma unroll 1
  for (int k0 = ks * 1024; k0 < kend; k0 += 32) {
    __syncthreads();              // prior MFMA done reading Asm/Bt
    *(f16x8*)bw_[0] = vv_[0];
    if (act1) *(f16x8*)bw_[1] = vv_[1];
#pragma unroll
    for (int i = 0; i < 4; ++i) gl_lds16(gA_[i] + k0, lA_[i]);
    __syncthreads();              // drains ds_writes + gl_lds
#pragma unroll
    for (int tap = 0; tap < 4; ++tap) {
      int dlt = (tap >> 1) * 64 + (tap & 1);
      f16x8 af[2], bf[2];
#pragma unroll
      for (int m = 0; m < 2; ++m) {
        int R = tap * 128 + wr * 32 + m * 16 + (lane & 15);
        int ph = (lane >> 4) ^ ((R >> 1) & 3);
        af[m] = *(const f16x8*)(Asm + R * 32 + ph * 8);
      }
#pragma unroll
      for (int n = 0; n < 2; ++n) {
        int pp = wc * 32 + n * 16 + (lane & 15) + dlt;
        int ph = (lane >> 4) ^ ((pp >> 3) & 3);
        bf[n] = *(const f16x8*)(Bt + pp * 40 + ph * 8);
      }
#pragma unroll
      for (int m = 0; m < 2; ++m)
#pragma unroll
        for (int n = 0; n < 2; ++n)
          acc[m][n] = __builtin_amdgcn_mfma_f32_16x16x32_f16(af[m], bf[n], acc[m][n], 0, 0, 0);
    }
    if (k0 + 32 < kend) LOADB(k0 + 32);
  }
#undef LOADB

  int cb = wr * 32 + (lane >> 4) * 4;
  int pb = p0 + wc * 32 + (lane & 15);
#pragma unroll
  for (int m = 0; m < 2; ++m)
#pragma unroll
    for (int n = 0; n < 2; ++n)
#pragma unroll
      for (int r = 0; r < 4; ++r) {
        int c = cb + m * 16 + r;
        int p = pb + n * 16;
        part[(((size_t)ks * 2 + batch) * CC + c) * L + p] = acc[m][n][r];
      }
}

// ---------------- kernel 5b: sum K-split partials, scale, border mask (vectorized) -------
__global__ __launch_bounds__(256) void k_agg_reduce(const float* __restrict__ part, float* __restrict__ out) {
  int idx = (blockIdx.x * 256 + threadIdx.x) * 4;   // 2*128*4096 total
  f32x4 s = {0.f, 0.f, 0.f, 0.f};
#pragma unroll
  for (int ks = 0; ks < 4; ++ks) {
    f32x4 v = *(const f32x4*)(part + (size_t)ks * (2 * CC * L) + idx);
#pragma unroll
    for (int e = 0; e < 4; ++e) s[e] += v[e];
  }
  int p = idx & (L - 1);
  int u = p >> 6, vv = p & 63;
  f32x4 o;
#pragma unroll
  for (int e = 0; e < 4; ++e) o[e] = (u < 63 && (vv + e) < 63) ? s[e] * 0.25f : 0.f;
  *(f32x4*)(out + idx) = o;
}

extern "C" void kernel_launch(void* const* d_in, const int* in_sizes, int n_in,
                              void* d_out, int out_size, void* d_ws, size_t ws_size,
                              hipStream_t stream) {
  const float* f = (const float*)d_in[0];
  const float* b = (const float*)d_in[1];
  const float* mask = (const float*)d_in[2];
  float* out = (float*)d_out;
  char* ws = (char*)d_ws;

  f16* P     = (f16*)(ws + 0);             // 67,108,864
  f16* S     = (f16*)(ws + 67108864);      // 67,108,864
  f16* bm    = (f16*)(ws + 134217728);     // 8,388,608
  float* part= (float*)(ws + 142606336);   // 16,777,216
  float* pmP = (float*)(ws + 159383552);   // 16,777,216 (512 chunks x 8192 f32)
  float* pl  = (float*)(ws + 176160768);   // 16,777,216
  float* mmv = (float*)(ws + 192937984);   // 16,384
  float* Mq  = (float*)(ws + 192954368);   // 32,768
  float* iLq = (float*)(ws + 192987136);   // 32,768
  f16* bT    = (f16*)(ws + 193019904);     // 2,097,152
  f16* fT    = (f16*)(ws + 195117056);     // 2,097,152
  float* ssq = (float*)(ws + 197214208);   // 32,768
  float* invn= (float*)(ws + 197246976);   // 32,768
  f16* zp    = (f16*)(ws + 197279744);     // 64
  float* zcnt= (float*)(ws + 197279872);   // 2,048

  k_repack<<<dim3(64, 4), dim3(256), 0, stream>>>(b, f, bT, fT, zp);
  k_ssq<<<dim3(16, 2), dim3(256), 0, stream>>>(b, ssq);
  k_norm<<<dim3(32), dim3(256), 0, stream>>>(ssq, invn);
  k_prep_bm<<<dim3(2048), dim3(256), 0, stream>>>(b, bm);
  k_prep_mm<<<dim3(16), dim3(256), 0, stream>>>(mask, mmv);
  k_zcnt<<<dim3(2), dim3(256), 0, stream>>>(mmv, zcnt);
  k_gemm_scores<<<dim3(32, 32, 2), dim3(256), 0, stream>>>(bT, fT, invn, zp, S);
  k_fuse_stats<<<dim3(2, 512, 2), dim3(256), 0, stream>>>(S, mmv, P, pmP, pl);
  k_fuse_stats_edge<<<dim3(512, 2), dim3(256), 0, stream>>>(S, mmv, P, pmP, pl);
  k_softmax_reduce<<<dim3(128), dim3(256), 0, stream>>>(pmP, pl, zcnt, Mq, iLq);
  k_agg<<<dim3(64, 4, 2), dim3(512), 0, stream>>>(P, pmP, mmv, Mq, iLq, bm, part);
  k_agg_reduce<<<dim3(1024), dim3(256), 0, stream>>>(part, out);
}